// Round 5
// baseline (27.203 us; speedup 1.0000x reference)
//
#include <hip/hip_runtime.h>
#include <hip/hip_bf16.h>

// RoPE: x (B,S,128) fp32, token_position (B,S) int32 (harness narrows int64).
// out[..., 2j]   = x[2j]*cos(p*f_j) - x[2j+1]*sin(p*f_j)
// out[..., 2j+1] = x[2j]*sin(p*f_j) + x[2j+1]*cos(p*f_j)
// f_j = theta^(-j/64), j = 0..63.
//
// Memory-bound: 64MiB in + 64MiB out + 0.5MiB pos = 134.7MB (algorithmic min).
// R2 (2-deep) and R4 (2-deep + NT stores) both 26.3us = 5.12 TB/s mixed R+W.
// R5: 4-deep MLP — all 4 x-loads + 4 pos-loads issued before any compute,
// __launch_bounds__(256,8) to pin full occupancy (8 blocks/CU = 32 waves/CU).
// If this is also 26.3us, we are at the mixed-stream HBM roofline.
//
// sin/cos via raw v_sin_f32/v_cos_f32 (input in REVOLUTIONS, fract-reduced);
// freqs precomputed in revolutions: f_rev = theta^(-j/64)/(2pi).
// Grid stride (524288) is a multiple of 32 -> quad index q loop-invariant;
// total4/stride = 8 exactly -> unroll-4 loop runs 2 iters, no tail.

typedef float f32x4 __attribute__((ext_vector_type(4)));

#define NEG_LOG2_THETA_OVER_64 (-0.2076205059304644f)  // -log2(10000)/64
#define INV_2PI                (0.15915494309189535f)

__device__ __forceinline__ f32x4 rope4(f32x4 v, float p, float f0, float f1) {
    float r0 = p * f0;
    float r1 = p * f1;
    r0 -= floorf(r0);                        // revolutions -> [0,1)
    r1 -= floorf(r1);
    const float s0 = __builtin_amdgcn_sinf(r0);
    const float c0 = __builtin_amdgcn_cosf(r0);
    const float s1 = __builtin_amdgcn_sinf(r1);
    const float c1 = __builtin_amdgcn_cosf(r1);
    f32x4 o;
    o.x = v.x * c0 - v.y * s0;
    o.y = v.x * s0 + v.y * c0;
    o.z = v.z * c1 - v.w * s1;
    o.w = v.z * s1 + v.w * c1;
    return o;
}

__global__ __launch_bounds__(256, 8)
void rope_kernel(const f32x4* __restrict__ x,
                 const int* __restrict__ pos,
                 f32x4* __restrict__ out,
                 int total4) {
    const int stride = gridDim.x * blockDim.x;   // 524288, multiple of 32
    const int i0 = blockIdx.x * blockDim.x + threadIdx.x;
    const int q = i0 & 31;                       // quad index within row
    const float j0 = (float)(2 * q);
    const float f0 = exp2f(j0 * NEG_LOG2_THETA_OVER_64) * INV_2PI;
    const float f1 = exp2f((j0 + 1.0f) * NEG_LOG2_THETA_OVER_64) * INV_2PI;

    int i = i0;
    // 4-deep: issue all 8 loads before any compute
    for (; i + 3 * stride < total4; i += 4 * stride) {
        const int ia = i;
        const int ib = i + stride;
        const int ic = i + 2 * stride;
        const int id = i + 3 * stride;
        const f32x4 va = x[ia];
        const f32x4 vb = x[ib];
        const f32x4 vc = x[ic];
        const f32x4 vd = x[id];
        const float pa = (float)pos[ia >> 5];
        const float pb = (float)pos[ib >> 5];
        const float pc = (float)pos[ic >> 5];
        const float pd = (float)pos[id >> 5];
        const f32x4 oa = rope4(va, pa, f0, f1);
        const f32x4 ob = rope4(vb, pb, f0, f1);
        const f32x4 oc = rope4(vc, pc, f0, f1);
        const f32x4 od = rope4(vd, pd, f0, f1);
        __builtin_nontemporal_store(oa, &out[ia]);
        __builtin_nontemporal_store(ob, &out[ib]);
        __builtin_nontemporal_store(oc, &out[ic]);
        __builtin_nontemporal_store(od, &out[id]);
    }
    for (; i < total4; i += stride) {            // generic tail (unused here)
        const f32x4 v = x[i];
        const float p = (float)pos[i >> 5];
        const f32x4 o = rope4(v, p, f0, f1);
        __builtin_nontemporal_store(o, &out[i]);
    }
}

extern "C" void kernel_launch(void* const* d_in, const int* in_sizes, int n_in,
                              void* d_out, int out_size, void* d_ws, size_t ws_size,
                              hipStream_t stream) {
    const f32x4* x   = (const f32x4*)d_in[0];
    const int*   pos = (const int*)d_in[1];
    f32x4*       out = (f32x4*)d_out;

    int total4 = out_size / 4;           // 16*8192*128/4 = 4,194,304 float4s
    int block = 256;
    int grid = (total4 + block - 1) / block;
    if (grid > 2048) grid = 2048;        // 8 float4 per thread
    rope_kernel<<<grid, block, 0, stream>>>(x, pos, out, total4);
}